// Round 1
// baseline (471.148 us; speedup 1.0000x reference)
//
#include <hip/hip_runtime.h>

// Problem constants
// B=8, T=8, S=500, F_IN=32, F=F_OUT=64, K=3, L=3, N=T*S=4000
#define BB 8
#define TT 8
#define SS 500
#define FIN 32
#define FF 64
#define NROWS (BB * TT * SS)   // 32000 rows of [.,FF]
#define TS_STRIDE (SS * FF)    // stride between t slices: 32000 floats

// ---------------------------------------------------------------------------
// lin1: xf[row, f] = sum_j x[row, j] * W1[f, j] + b1[f]   (row = b*T*S + t*S + s)
// ---------------------------------------------------------------------------
__global__ __launch_bounds__(256) void lin1_k(const float* __restrict__ x,
                                              const float* __restrict__ W1,
                                              const float* __restrict__ b1,
                                              float* __restrict__ xf) {
    __shared__ float W[FIN][FF];   // transposed: W[j][f]
    __shared__ float bl[FF];
    int tid = threadIdx.x;
    for (int i = tid; i < FIN * FF; i += 256) {
        int f = i >> 5, j = i & 31;          // W1 is [64][32]
        W[j][f] = W1[i];
    }
    if (tid < FF) bl[tid] = b1[tid];
    __syncthreads();
    int f  = tid & 63;
    int ty = tid >> 6;                        // 4 rows per block
    int row = blockIdx.x * 4 + ty;            // 32000 rows -> 8000 blocks
    const float* xr = x + (size_t)row * FIN;
    float acc = bl[f];
    #pragma unroll
    for (int j = 0; j < FIN; ++j) acc += xr[j] * W[j][f];
    xf[(size_t)row * FF + f] = acc;
}

// ---------------------------------------------------------------------------
// spatial_mm: u[bt, s, f] = sum_{s'} As[s, s'] * v[bt, s', f]
// grid: (8 s-tiles, 64 bt), block 256
// ---------------------------------------------------------------------------
__global__ __launch_bounds__(256) void spatial_mm(const float* __restrict__ As,
                                                  const float* __restrict__ v,
                                                  float* __restrict__ u) {
    int bt = blockIdx.y;
    int s0 = blockIdx.x * 64;
    const float* vb = v + (size_t)bt * SS * FF;
    float*       ub = u + (size_t)bt * SS * FF;

    __shared__ float AsT[64][65];  // AsT[k][s], stride 65 breaks bank conflicts
    __shared__ float Vt[64][64];   // Vt[k][f]

    int tid = threadIdx.x;
    int tx = tid & 15;   // f-group (4 f each)
    int ty = tid >> 4;   // s-group base (16 groups)

    float acc[4][4] = {{0.f}};

    for (int k0 = 0; k0 < SS; k0 += 64) {
        // stage As[s0+r][k0+c] -> AsT[c][r], zero-padded
        #pragma unroll
        for (int rr = 0; rr < 64; rr += 16) {
            int r  = ty + rr;
            int c4 = tx * 4;
            int gs = s0 + r, gk = k0 + c4;
            float a0 = 0.f, a1 = 0.f, a2 = 0.f, a3 = 0.f;
            if (gs < SS) {
                const float* p = As + (size_t)gs * SS + gk;
                if (gk + 3 < SS) {
                    float4 t = *(const float4*)p;   // row stride 2000B, 16B-aligned
                    a0 = t.x; a1 = t.y; a2 = t.z; a3 = t.w;
                } else {
                    if (gk + 0 < SS) a0 = p[0];
                    if (gk + 1 < SS) a1 = p[1];
                    if (gk + 2 < SS) a2 = p[2];
                    if (gk + 3 < SS) a3 = p[3];
                }
            }
            AsT[c4 + 0][r] = a0; AsT[c4 + 1][r] = a1;
            AsT[c4 + 2][r] = a2; AsT[c4 + 3][r] = a3;
        }
        // stage v[bt][k0+r][f] -> Vt[r][f], zero-padded
        #pragma unroll
        for (int rr = 0; rr < 64; rr += 16) {
            int r = ty + rr;
            int gk = k0 + r;
            float4 t = make_float4(0.f, 0.f, 0.f, 0.f);
            if (gk < SS) t = *(const float4*)(vb + (size_t)gk * FF + tx * 4);
            *(float4*)&Vt[r][tx * 4] = t;
        }
        __syncthreads();

        #pragma unroll 8
        for (int k = 0; k < 64; ++k) {       // zero padding makes full 64 safe
            float av0 = AsT[k][ty * 4 + 0];
            float av1 = AsT[k][ty * 4 + 1];
            float av2 = AsT[k][ty * 4 + 2];
            float av3 = AsT[k][ty * 4 + 3];
            float4 vv = *(const float4*)&Vt[k][tx * 4];
            acc[0][0] += av0 * vv.x; acc[0][1] += av0 * vv.y; acc[0][2] += av0 * vv.z; acc[0][3] += av0 * vv.w;
            acc[1][0] += av1 * vv.x; acc[1][1] += av1 * vv.y; acc[1][2] += av1 * vv.z; acc[1][3] += av1 * vv.w;
            acc[2][0] += av2 * vv.x; acc[2][1] += av2 * vv.y; acc[2][2] += av2 * vv.z; acc[2][3] += av2 * vv.w;
            acc[3][0] += av3 * vv.x; acc[3][1] += av3 * vv.y; acc[3][2] += av3 * vv.z; acc[3][3] += av3 * vv.w;
        }
        __syncthreads();
    }

    #pragma unroll
    for (int i = 0; i < 4; ++i) {
        int gs = s0 + ty * 4 + i;
        if (gs < SS) {
            float4 t = make_float4(acc[i][0], acc[i][1], acc[i][2], acc[i][3]);
            *(float4*)(ub + (size_t)gs * FF + tx * 4) = t;
        }
    }
}

// ---------------------------------------------------------------------------
// combine: y[b,t,s,f] = s0 v + s1 u + sum_{t'} At[t,t'] (s2 v[t'] + s3 u[t'])
// one thread per (b,s,f); 256000 threads
// ---------------------------------------------------------------------------
__global__ __launch_bounds__(256) void combine_k(const float* __restrict__ v,
                                                 const float* __restrict__ u,
                                                 const float* __restrict__ At,
                                                 const float* __restrict__ sc,
                                                 float* __restrict__ y) {
    __shared__ float Atl[TT * TT];
    __shared__ float sl[4];
    int tid = threadIdx.x;
    if (tid < TT * TT) Atl[tid] = At[tid];
    if (tid < 4) sl[tid] = sc[tid];
    __syncthreads();

    int idx = blockIdx.x * 256 + tid;        // over B*S*F = 256000
    int f = idx & 63;
    int rest = idx >> 6;
    int si = rest % SS;
    int b  = rest / SS;
    size_t base = ((size_t)b * TT * SS + si) * FF + f;

    float vv[TT], uu[TT], ww[TT];
    #pragma unroll
    for (int t = 0; t < TT; ++t) {
        vv[t] = v[base + (size_t)t * TS_STRIDE];
        uu[t] = u[base + (size_t)t * TS_STRIDE];
    }
    float s0 = sl[0], s1 = sl[1], s2 = sl[2], s3 = sl[3];
    #pragma unroll
    for (int t = 0; t < TT; ++t) ww[t] = s2 * vv[t] + s3 * uu[t];
    #pragma unroll
    for (int t = 0; t < TT; ++t) {
        float r = s0 * vv[t] + s1 * uu[t];
        #pragma unroll
        for (int tp = 0; tp < TT; ++tp) r += Atl[t * TT + tp] * ww[tp];
        y[base + (size_t)t * TS_STRIDE] = r;
    }
}

// ---------------------------------------------------------------------------
// hcombine: out[row,f] = tanh( sum_j y0*H0 + y1*H1 + y2*H2 )
// H points at H[l]: [3][64][64] (j outer, f inner)
// ---------------------------------------------------------------------------
__global__ __launch_bounds__(256) void hcombine_k(const float* __restrict__ y0,
                                                  const float* __restrict__ y1,
                                                  const float* __restrict__ y2,
                                                  const float* __restrict__ H,
                                                  float* __restrict__ out) {
    __shared__ float Hl[3][FF][FF];   // 48 KB
    int tid = threadIdx.x;
    for (int i = tid; i < 3 * FF * FF; i += 256) ((float*)Hl)[i] = H[i];
    __syncthreads();

    int tx = tid & 15, ty = tid >> 4;
    int row = blockIdx.x * 16 + ty;    // 32000 rows -> 2000 blocks
    const float* p0 = y0 + (size_t)row * FF;
    const float* p1 = y1 + (size_t)row * FF;
    const float* p2 = y2 + (size_t)row * FF;
    int f4 = tx * 4;

    float acc0 = 0.f, acc1 = 0.f, acc2 = 0.f, acc3 = 0.f;
    #pragma unroll 8
    for (int j = 0; j < FF; ++j) {
        float a0 = p0[j], a1 = p1[j], a2 = p2[j];
        float4 h0 = *(const float4*)&Hl[0][j][f4];
        float4 h1 = *(const float4*)&Hl[1][j][f4];
        float4 h2 = *(const float4*)&Hl[2][j][f4];
        acc0 += a0 * h0.x + a1 * h1.x + a2 * h2.x;
        acc1 += a0 * h0.y + a1 * h1.y + a2 * h2.y;
        acc2 += a0 * h0.z + a1 * h1.z + a2 * h2.z;
        acc3 += a0 * h0.w + a1 * h1.w + a2 * h2.w;
    }
    float4 r;
    r.x = tanhf(acc0); r.y = tanhf(acc1); r.z = tanhf(acc2); r.w = tanhf(acc3);
    *(float4*)(out + (size_t)row * FF + f4) = r;
}

// ---------------------------------------------------------------------------
// zred: z[b,s,f] = sum_t merge[t] * xf[b,t,s,f]
// ---------------------------------------------------------------------------
__global__ __launch_bounds__(256) void zred_k(const float* __restrict__ xf,
                                              const float* __restrict__ merge,
                                              float* __restrict__ z) {
    __shared__ float m[TT];
    if (threadIdx.x < TT) m[threadIdx.x] = merge[threadIdx.x];
    __syncthreads();
    int idx = blockIdx.x * 256 + threadIdx.x;   // B*S*F = 256000
    int f = idx & 63;
    int rest = idx >> 6;
    int si = rest % SS;
    int b  = rest / SS;
    size_t base = ((size_t)b * TT * SS + si) * FF + f;
    float acc = 0.f;
    #pragma unroll
    for (int t = 0; t < TT; ++t) acc += m[t] * xf[base + (size_t)t * TS_STRIDE];
    z[idx] = acc;
}

// ---------------------------------------------------------------------------
// lin2: out[row,f] = sum_j z[row,j] * W2[f,j] + b2[f] * sum(merge)
// rows = B*S = 4000
// ---------------------------------------------------------------------------
__global__ __launch_bounds__(256) void lin2_k(const float* __restrict__ z,
                                              const float* __restrict__ W2,
                                              const float* __restrict__ b2,
                                              const float* __restrict__ merge,
                                              float* __restrict__ out) {
    __shared__ float W[FF][FF];   // transposed: W[j][f]
    __shared__ float bl[FF];
    __shared__ float msum_s;
    int tid = threadIdx.x;
    for (int i = tid; i < FF * FF; i += 256) {
        int f = i >> 6, j = i & 63;
        W[j][f] = W2[i];
    }
    if (tid < FF) bl[tid] = b2[tid];
    if (tid == 0) {
        float msum = 0.f;
        for (int t = 0; t < TT; ++t) msum += merge[t];
        msum_s = msum;
    }
    __syncthreads();
    int f  = tid & 63;
    int ty = tid >> 6;
    int row = blockIdx.x * 4 + ty;     // 4000 rows -> 1000 blocks
    const float* zr = z + (size_t)row * FF;
    float acc = bl[f] * msum_s;
    #pragma unroll
    for (int j = 0; j < FF; ++j) acc += zr[j] * W[j][f];
    out[(size_t)row * FF + f] = acc;
}

// ---------------------------------------------------------------------------
extern "C" void kernel_launch(void* const* d_in, const int* in_sizes, int n_in,
                              void* d_out, int out_size, void* d_ws, size_t ws_size,
                              hipStream_t stream) {
    const float* x     = (const float*)d_in[0];
    const float* At    = (const float*)d_in[1];
    const float* As    = (const float*)d_in[2];
    const float* sc    = (const float*)d_in[3];
    const float* H     = (const float*)d_in[4];
    const float* W1    = (const float*)d_in[5];
    const float* b1    = (const float*)d_in[6];
    const float* W2    = (const float*)d_in[7];
    const float* b2    = (const float*)d_in[8];
    const float* merge = (const float*)d_in[9];
    float* out = (float*)d_out;

    float* ws = (float*)d_ws;
    const size_t NB = (size_t)NROWS * FF;   // 2,048,000 floats
    float* xfA  = ws;
    float* xfB  = ws + NB;
    float* ubuf = ws + 2 * NB;
    float* y1   = ws + 3 * NB;
    float* y2   = ws + 4 * NB;
    float* z    = ws + 5 * NB;              // 256,000 floats

    lin1_k<<<NROWS / 4, 256, 0, stream>>>(x, W1, b1, xfA);

    float* cur = xfA;
    float* nxt = xfB;
    for (int l = 0; l < 3; ++l) {
        spatial_mm<<<dim3(8, BB * TT), 256, 0, stream>>>(As, cur, ubuf);
        combine_k<<<1000, 256, 0, stream>>>(cur, ubuf, At, sc, y1);
        spatial_mm<<<dim3(8, BB * TT), 256, 0, stream>>>(As, y1, ubuf);
        combine_k<<<1000, 256, 0, stream>>>(y1, ubuf, At, sc, y2);
        hcombine_k<<<NROWS / 16, 256, 0, stream>>>(cur, y1, y2,
                                                   H + (size_t)l * 3 * FF * FF, nxt);
        float* tmp = cur; cur = nxt; nxt = tmp;
    }
    // result now in `cur` (xfB after 3 swaps)
    zred_k<<<1000, 256, 0, stream>>>(cur, merge, z);
    lin2_k<<<1000, 256, 0, stream>>>(z, W2, b2, merge, out);
}

// Round 2
// 344.508 us; speedup vs baseline: 1.3676x; 1.3676x over previous
//
#include <hip/hip_runtime.h>

// Problem constants
// B=8, T=8, S=500, F_IN=32, F=F_OUT=64, K=3, L=3, N=T*S=4000
#define BB 8
#define TT 8
#define SS 500
#define FIN 32
#define FF 64
#define NROWS (BB * TT * SS)   // 32000 rows of [.,FF]
#define TS_STRIDE (SS * FF)    // stride between t slices: 32000 floats

typedef short bf16x8 __attribute__((ext_vector_type(8)));
typedef float floatx4 __attribute__((ext_vector_type(4)));

__device__ __forceinline__ unsigned f2bf(float x) {
    unsigned u = __builtin_bit_cast(unsigned, x);
    return (u + 0x7FFFu + ((u >> 16) & 1u)) >> 16;   // RNE bf16, returned in low 16
}

// ---------------------------------------------------------------------------
// lin1: xf[row, f] = sum_j x[row, j] * W1[f, j] + b1[f]
// ---------------------------------------------------------------------------
__global__ __launch_bounds__(256) void lin1_k(const float* __restrict__ x,
                                              const float* __restrict__ W1,
                                              const float* __restrict__ b1,
                                              float* __restrict__ xf) {
    __shared__ float W[FIN][FF];   // transposed: W[j][f]
    __shared__ float bl[FF];
    int tid = threadIdx.x;
    for (int i = tid; i < FIN * FF; i += 256) {
        int f = i >> 5, j = i & 31;          // W1 is [64][32]
        W[j][f] = W1[i];
    }
    if (tid < FF) bl[tid] = b1[tid];
    __syncthreads();
    int f  = tid & 63;
    int ty = tid >> 6;                        // 4 rows per block
    int row = blockIdx.x * 4 + ty;            // 32000 rows -> 8000 blocks
    const float* xr = x + (size_t)row * FIN;
    float acc = bl[f];
    #pragma unroll
    for (int j = 0; j < FIN; ++j) acc += xr[j] * W[j][f];
    xf[(size_t)row * FF + f] = acc;
}

// ---------------------------------------------------------------------------
// spatial_mm (MFMA bf16): u[bt, s, f] = sum_{s'} As[s, s'] * v[bt, s', f]
// grid: (8 s-tiles, 64 bt), block 256 = 4 waves.
// Block tile M=64(s) x N=64(f), K looped 32 at a time (bf16 staged in LDS,
// fp32 accumulate in MFMA). Wave w owns s-rows [w*16, w*16+16), all 64 f.
// LDS k-stride 72 bf16 => 144B rows (16B aligned, bank-step 4 => conflict-free
// frag reads).
// ---------------------------------------------------------------------------
#define LDK 72

__global__ __launch_bounds__(256) void spatial_mm(const float* __restrict__ As,
                                                  const float* __restrict__ v,
                                                  float* __restrict__ u) {
    __shared__ unsigned short Abf[64 * LDK];   // Abf[s_local][k_local]
    __shared__ unsigned short Vbf[64 * LDK];   // Vbf[f][k_local]  (transposed)

    int bt = blockIdx.y;
    int s0 = blockIdx.x * 64;
    const float* vb = v + (size_t)bt * SS * FF;
    float*       ub = u + (size_t)bt * SS * FF;

    int tid  = threadIdx.x;
    int wave = tid >> 6;
    int lane = tid & 63;
    int l16  = lane & 15;
    int quad = lane >> 4;

    // A-staging indices: 64 rows x 32 cols, 8 consecutive floats per thread
    int arw = tid >> 2;            // 0..63  (s row within tile)
    int ac4 = (tid & 3) * 8;       // k col base
    // V-staging indices: thread reads k rows 2*vty, 2*vty+1 at f = vtx*4..+3
    int vty = tid >> 4;            // 0..15
    int vtx = tid & 15;

    floatx4 acc[4] = {};

    for (int k0 = 0; k0 < SS; k0 += 32) {
        // ---- stage A: As[s0+arw][k0+ac4 .. +7] -> Abf[arw][ac4..], bf16
        {
            float a[8];
            #pragma unroll
            for (int j = 0; j < 8; ++j) a[j] = 0.f;
            int gs = s0 + arw;
            int gk = k0 + ac4;
            if (gs < SS) {
                const float* p = As + (size_t)gs * SS + gk;
                if (gk + 7 < SS) {
                    float4 t0 = *(const float4*)p;
                    float4 t1 = *(const float4*)(p + 4);
                    a[0]=t0.x; a[1]=t0.y; a[2]=t0.z; a[3]=t0.w;
                    a[4]=t1.x; a[5]=t1.y; a[6]=t1.z; a[7]=t1.w;
                } else {
                    #pragma unroll
                    for (int j = 0; j < 8; ++j) if (gk + j < SS) a[j] = p[j];
                }
            }
            int4 w4;
            w4.x = (int)(f2bf(a[0]) | (f2bf(a[1]) << 16));
            w4.y = (int)(f2bf(a[2]) | (f2bf(a[3]) << 16));
            w4.z = (int)(f2bf(a[4]) | (f2bf(a[5]) << 16));
            w4.w = (int)(f2bf(a[6]) | (f2bf(a[7]) << 16));
            *(int4*)&Abf[arw * LDK + ac4] = w4;     // 16B aligned (144*arw + 16*(tid&3))
        }
        // ---- stage V transposed: v[k0+2vty(+1)][vtx*4..+3] -> Vbf[f][k], bf16 pairs
        {
            int k1 = k0 + 2 * vty, k2 = k1 + 1;
            float4 r0 = make_float4(0.f, 0.f, 0.f, 0.f);
            float4 r1 = make_float4(0.f, 0.f, 0.f, 0.f);
            if (k1 < SS) r0 = *(const float4*)(vb + (size_t)k1 * FF + vtx * 4);
            if (k2 < SS) r1 = *(const float4*)(vb + (size_t)k2 * FF + vtx * 4);
            unsigned p0 = f2bf(r0.x) | (f2bf(r1.x) << 16);
            unsigned p1 = f2bf(r0.y) | (f2bf(r1.y) << 16);
            unsigned p2 = f2bf(r0.z) | (f2bf(r1.z) << 16);
            unsigned p3 = f2bf(r0.w) | (f2bf(r1.w) << 16);
            int kc = 2 * vty;
            *(unsigned*)&Vbf[(vtx * 4 + 0) * LDK + kc] = p0;
            *(unsigned*)&Vbf[(vtx * 4 + 1) * LDK + kc] = p1;
            *(unsigned*)&Vbf[(vtx * 4 + 2) * LDK + kc] = p2;
            *(unsigned*)&Vbf[(vtx * 4 + 3) * LDK + kc] = p3;
        }
        __syncthreads();

        // ---- MFMA: A[m=l16][k=quad*8+j], B[k=quad*8+j][n=l16]
        bf16x8 afrag = *(const bf16x8*)&Abf[(wave * 16 + l16) * LDK + quad * 8];
        #pragma unroll
        for (int nt = 0; nt < 4; ++nt) {
            bf16x8 bfrag = *(const bf16x8*)&Vbf[(nt * 16 + l16) * LDK + quad * 8];
            acc[nt] = __builtin_amdgcn_mfma_f32_16x16x32_bf16(afrag, bfrag, acc[nt], 0, 0, 0);
        }
        __syncthreads();
    }

    // C/D layout: col(f)=lane&15, row(s)=quad*4+reg
    #pragma unroll
    for (int nt = 0; nt < 4; ++nt) {
        int f = nt * 16 + l16;
        #pragma unroll
        for (int r = 0; r < 4; ++r) {
            int srow = s0 + wave * 16 + quad * 4 + r;
            if (srow < SS) ub[(size_t)srow * FF + f] = acc[nt][r];
        }
    }
}

// ---------------------------------------------------------------------------
// combine: y[b,t,s,f] = s0 v + s1 u + sum_{t'} At[t,t'] (s2 v[t'] + s3 u[t'])
// ---------------------------------------------------------------------------
__global__ __launch_bounds__(256) void combine_k(const float* __restrict__ v,
                                                 const float* __restrict__ u,
                                                 const float* __restrict__ At,
                                                 const float* __restrict__ sc,
                                                 float* __restrict__ y) {
    __shared__ float Atl[TT * TT];
    __shared__ float sl[4];
    int tid = threadIdx.x;
    if (tid < TT * TT) Atl[tid] = At[tid];
    if (tid < 4) sl[tid] = sc[tid];
    __syncthreads();

    int idx = blockIdx.x * 256 + tid;        // over B*S*F = 256000
    int f = idx & 63;
    int rest = idx >> 6;
    int si = rest % SS;
    int b  = rest / SS;
    size_t base = ((size_t)b * TT * SS + si) * FF + f;

    float vv[TT], uu[TT], ww[TT];
    #pragma unroll
    for (int t = 0; t < TT; ++t) {
        vv[t] = v[base + (size_t)t * TS_STRIDE];
        uu[t] = u[base + (size_t)t * TS_STRIDE];
    }
    float s0 = sl[0], s1 = sl[1], s2 = sl[2], s3 = sl[3];
    #pragma unroll
    for (int t = 0; t < TT; ++t) ww[t] = s2 * vv[t] + s3 * uu[t];
    #pragma unroll
    for (int t = 0; t < TT; ++t) {
        float r = s0 * vv[t] + s1 * uu[t];
        #pragma unroll
        for (int tp = 0; tp < TT; ++tp) r += Atl[t * TT + tp] * ww[tp];
        y[base + (size_t)t * TS_STRIDE] = r;
    }
}

// ---------------------------------------------------------------------------
// hcombine: out[row,f] = tanh( sum_j y0*H0 + y1*H1 + y2*H2 )
// ---------------------------------------------------------------------------
__global__ __launch_bounds__(256) void hcombine_k(const float* __restrict__ y0,
                                                  const float* __restrict__ y1,
                                                  const float* __restrict__ y2,
                                                  const float* __restrict__ H,
                                                  float* __restrict__ out) {
    __shared__ float Hl[3][FF][FF];   // 48 KB
    int tid = threadIdx.x;
    for (int i = tid; i < 3 * FF * FF; i += 256) ((float*)Hl)[i] = H[i];
    __syncthreads();

    int tx = tid & 15, ty = tid >> 4;
    int row = blockIdx.x * 16 + ty;    // 32000 rows -> 2000 blocks
    const float* p0 = y0 + (size_t)row * FF;
    const float* p1 = y1 + (size_t)row * FF;
    const float* p2 = y2 + (size_t)row * FF;
    int f4 = tx * 4;

    float acc0 = 0.f, acc1 = 0.f, acc2 = 0.f, acc3 = 0.f;
    #pragma unroll 8
    for (int j = 0; j < FF; ++j) {
        float a0 = p0[j], a1 = p1[j], a2 = p2[j];
        float4 h0 = *(const float4*)&Hl[0][j][f4];
        float4 h1 = *(const float4*)&Hl[1][j][f4];
        float4 h2 = *(const float4*)&Hl[2][j][f4];
        acc0 += a0 * h0.x + a1 * h1.x + a2 * h2.x;
        acc1 += a0 * h0.y + a1 * h1.y + a2 * h2.y;
        acc2 += a0 * h0.z + a1 * h1.z + a2 * h2.z;
        acc3 += a0 * h0.w + a1 * h1.w + a2 * h2.w;
    }
    float4 r;
    r.x = tanhf(acc0); r.y = tanhf(acc1); r.z = tanhf(acc2); r.w = tanhf(acc3);
    *(float4*)(out + (size_t)row * FF + f4) = r;
}

// ---------------------------------------------------------------------------
// zred: z[b,s,f] = sum_t merge[t] * xf[b,t,s,f]
// ---------------------------------------------------------------------------
__global__ __launch_bounds__(256) void zred_k(const float* __restrict__ xf,
                                              const float* __restrict__ merge,
                                              float* __restrict__ z) {
    __shared__ float m[TT];
    if (threadIdx.x < TT) m[threadIdx.x] = merge[threadIdx.x];
    __syncthreads();
    int idx = blockIdx.x * 256 + threadIdx.x;   // B*S*F = 256000
    int f = idx & 63;
    int rest = idx >> 6;
    int si = rest % SS;
    int b  = rest / SS;
    size_t base = ((size_t)b * TT * SS + si) * FF + f;
    float acc = 0.f;
    #pragma unroll
    for (int t = 0; t < TT; ++t) acc += m[t] * xf[base + (size_t)t * TS_STRIDE];
    z[idx] = acc;
}

// ---------------------------------------------------------------------------
// lin2: out[row,f] = sum_j z[row,j] * W2[f,j] + b2[f] * sum(merge)
// ---------------------------------------------------------------------------
__global__ __launch_bounds__(256) void lin2_k(const float* __restrict__ z,
                                              const float* __restrict__ W2,
                                              const float* __restrict__ b2,
                                              const float* __restrict__ merge,
                                              float* __restrict__ out) {
    __shared__ float W[FF][FF];   // transposed: W[j][f]
    __shared__ float bl[FF];
    __shared__ float msum_s;
    int tid = threadIdx.x;
    for (int i = tid; i < FF * FF; i += 256) {
        int f = i >> 6, j = i & 63;
        W[j][f] = W2[i];
    }
    if (tid < FF) bl[tid] = b2[tid];
    if (tid == 0) {
        float msum = 0.f;
        for (int t = 0; t < TT; ++t) msum += merge[t];
        msum_s = msum;
    }
    __syncthreads();
    int f  = tid & 63;
    int ty = tid >> 6;
    int row = blockIdx.x * 4 + ty;     // 4000 rows -> 1000 blocks
    const float* zr = z + (size_t)row * FF;
    float acc = bl[f] * msum_s;
    #pragma unroll
    for (int j = 0; j < FF; ++j) acc += zr[j] * W[j][f];
    out[(size_t)row * FF + f] = acc;
}

// ---------------------------------------------------------------------------
extern "C" void kernel_launch(void* const* d_in, const int* in_sizes, int n_in,
                              void* d_out, int out_size, void* d_ws, size_t ws_size,
                              hipStream_t stream) {
    const float* x     = (const float*)d_in[0];
    const float* At    = (const float*)d_in[1];
    const float* As    = (const float*)d_in[2];
    const float* sc    = (const float*)d_in[3];
    const float* H     = (const float*)d_in[4];
    const float* W1    = (const float*)d_in[5];
    const float* b1    = (const float*)d_in[6];
    const float* W2    = (const float*)d_in[7];
    const float* b2    = (const float*)d_in[8];
    const float* merge = (const float*)d_in[9];
    float* out = (float*)d_out;

    float* ws = (float*)d_ws;
    const size_t NB = (size_t)NROWS * FF;   // 2,048,000 floats
    float* xfA  = ws;
    float* xfB  = ws + NB;
    float* ubuf = ws + 2 * NB;
    float* y1   = ws + 3 * NB;
    float* y2   = ws + 4 * NB;
    float* z    = ws + 5 * NB;              // 256,000 floats

    lin1_k<<<NROWS / 4, 256, 0, stream>>>(x, W1, b1, xfA);

    float* cur = xfA;
    float* nxt = xfB;
    for (int l = 0; l < 3; ++l) {
        spatial_mm<<<dim3(8, BB * TT), 256, 0, stream>>>(As, cur, ubuf);
        combine_k<<<1000, 256, 0, stream>>>(cur, ubuf, At, sc, y1);
        spatial_mm<<<dim3(8, BB * TT), 256, 0, stream>>>(As, y1, ubuf);
        combine_k<<<1000, 256, 0, stream>>>(y1, ubuf, At, sc, y2);
        hcombine_k<<<NROWS / 16, 256, 0, stream>>>(cur, y1, y2,
                                                   H + (size_t)l * 3 * FF * FF, nxt);
        float* tmp = cur; cur = nxt; nxt = tmp;
    }
    // result now in `cur`
    zred_k<<<1000, 256, 0, stream>>>(cur, merge, z);
    lin2_k<<<1000, 256, 0, stream>>>(z, W2, b2, merge, out);
}